// Round 10
// baseline (264.108 us; speedup 1.0000x reference)
//
#include <hip/hip_runtime.h>
#include <math.h>

// Sizes (fixed by the problem)
#define Bb   256
#define Tt   512
#define Dd   768
#define Ff   1024
#define Hh   8
#define HIDh 512
#define OUTo 256

// ===========================================================================
// prep: all weight layout transforms in ONE kernel (4480 blocks, float4 I/O).
// ===========================================================================
__device__ __forceinline__ void tr_tile4(const float* __restrict__ in,
                                         float* __restrict__ out,
                                         int R, int C, int cx, int ry,
                                         float (*tile)[33])
{
    int c0 = cx * 32, r0 = ry * 32;
    int r  = threadIdx.x >> 3;          // 0..31
    int c4 = (threadIdx.x & 7) * 4;     // 0,4,...,28
    float4 v = *(const float4*)&in[(size_t)(r0 + r) * C + c0 + c4];
    tile[r][c4 + 0] = v.x;
    tile[r][c4 + 1] = v.y;
    tile[r][c4 + 2] = v.z;
    tile[r][c4 + 3] = v.w;
    __syncthreads();
    float4 o;
    o.x = tile[c4 + 0][r];
    o.y = tile[c4 + 1][r];
    o.z = tile[c4 + 2][r];
    o.w = tile[c4 + 3][r];
    *(float4*)&out[(size_t)(c0 + r) * R + r0 + c4] = o;
}

__global__ __launch_bounds__(256) void prep(const float* __restrict__ Wq, float* __restrict__ WqT,
                                            const float* __restrict__ Wo, float* __restrict__ WoT,
                                            const float* __restrict__ Wv, float* __restrict__ WvT,
                                            const float* __restrict__ W1, float* __restrict__ W1T,
                                            const float* __restrict__ W2, float* __restrict__ W2T,
                                            const float* __restrict__ Wk, float* __restrict__ WkT)
{
    __shared__ float tile[32][33];
    int idx = blockIdx.x;
    if (idx < 1024) {
        tr_tile4(Wq, WqT, 1024, 1024, idx & 31, idx >> 5, tile);
    } else if (idx < 2048) {
        int i2 = idx - 1024;
        tr_tile4(Wo, WoT, 1024, 1024, i2 & 31, i2 >> 5, tile);
    } else if (idx < 2816) {
        int i2 = idx - 2048;                 // Wv: [1024][768]
        tr_tile4(Wv, WvT, 1024, 768, i2 % 24, i2 / 24, tile);
    } else if (idx < 3328) {
        int i2 = idx - 2816;                 // W1: [512][1024]
        tr_tile4(W1, W1T, 512, 1024, i2 & 31, i2 >> 5, tile);
    } else if (idx < 3456) {
        int i2 = idx - 3328;                 // W2: [256][512]
        tr_tile4(W2, W2T, 256, 512, i2 & 15, i2 >> 4, tile);
    } else {
        int i2 = idx - 3456;                 // Wk permute: (h,i,j)->[i][h*768+j]
        int i = i2 >> 3, h = i2 & 7;
        if (threadIdx.x < 192) {
            int j = threadIdx.x * 4;
            *(float4*)&WkT[(size_t)(i * 8 + h) * 768 + j] =
                *(const float4*)&Wk[(size_t)(h * 128 + i) * 768 + j];
        }
    }
}

// 16-FMA micro-tile (4 w-float4 x 1 a-float4)
#define FMA16(acc, a, w0, w1, w2, w3)                         \
    acc.x = fmaf(a.x, w0.x, acc.x); acc.y = fmaf(a.x, w0.y, acc.y); \
    acc.z = fmaf(a.x, w0.z, acc.z); acc.w = fmaf(a.x, w0.w, acc.w); \
    acc.x = fmaf(a.y, w1.x, acc.x); acc.y = fmaf(a.y, w1.y, acc.y); \
    acc.z = fmaf(a.y, w1.z, acc.z); acc.w = fmaf(a.y, w1.w, acc.w); \
    acc.x = fmaf(a.z, w2.x, acc.x); acc.y = fmaf(a.z, w2.y, acc.y); \
    acc.z = fmaf(a.z, w2.z, acc.z); acc.w = fmaf(a.z, w2.w, acc.w); \
    acc.x = fmaf(a.w, w3.x, acc.x); acc.y = fmaf(a.w, w3.y, acc.y); \
    acc.z = fmaf(a.w, w3.z, acc.z); acc.w = fmaf(a.w, w3.w, acc.w);

// ===========================================================================
// Split-K GEMM (plain A): Cslab[ks] = A-slice @ Wt-slice. RT=64. (R6-proven)
// ===========================================================================
template<int CT, int RT, int R, int KS>
__global__ __launch_bounds__(256, 4) void gemm_sk(const float* __restrict__ A, int strideA,
                                                  const float* __restrict__ Wt, int N,
                                                  float* __restrict__ Cslab, int M)
{
    constexpr int CG = CT / 4;
    constexpr int RG = RT / R;
    static_assert(CG * RG == 256, "bad tile");
    const int cg = threadIdx.x % CG;
    const int rg = threadIdx.x / CG;
    const int n0 = blockIdx.x * CT + cg * 4;
    const int r0 = blockIdx.y * RT;
    const int k0 = blockIdx.z * KS;

    __shared__ float As[RT][KS + 4];
    for (int e = threadIdx.x * 4; e < RT * KS; e += 1024) {
        int r = e / KS, k = e % KS;
        *(float4*)&As[r][k] = *(const float4*)&A[(size_t)(r0 + r) * strideA + k0 + k];
    }
    __syncthreads();

    float4 acc[R];
#pragma unroll
    for (int rr = 0; rr < R; ++rr) acc[rr] = make_float4(0.f, 0.f, 0.f, 0.f);
    const float* wp = Wt + (size_t)k0 * N + n0;
#pragma unroll 2
    for (int k = 0; k < KS; k += 4) {
        float4 w0 = *(const float4*)&wp[(size_t)(k + 0) * N];
        float4 w1 = *(const float4*)&wp[(size_t)(k + 1) * N];
        float4 w2 = *(const float4*)&wp[(size_t)(k + 2) * N];
        float4 w3 = *(const float4*)&wp[(size_t)(k + 3) * N];
#pragma unroll
        for (int rr = 0; rr < R; ++rr) {
            float4 a = *(const float4*)&As[rg * R + rr][k];
            FMA16(acc[rr], a, w0, w1, w2, w3)
        }
    }
    float* cp = Cslab + (size_t)blockIdx.z * M * N;
#pragma unroll
    for (int rr = 0; rr < R; ++rr)
        *(float4*)&cp[(size_t)(r0 + rg * R + rr) * N + n0] = acc[rr];
}

// ===========================================================================
// reduce_add: out[i] = sum_s slabs[s][i] + bias[i % N]
// ===========================================================================
template<int S>
__global__ __launch_bounds__(256) void reduce_add(const float* __restrict__ slabs,
                                                  size_t slabstride,
                                                  const float* __restrict__ bias,
                                                  float* __restrict__ out, int N, int total)
{
    int i4 = (blockIdx.x * 256 + threadIdx.x) * 4;
    if (i4 >= total) return;
    float4 acc = *(const float4*)&bias[i4 % N];
#pragma unroll
    for (int s = 0; s < S; ++s) {
        float4 v = *(const float4*)(slabs + (size_t)s * slabstride + i4);
        acc.x += v.x; acc.y += v.y; acc.z += v.z; acc.w += v.w;
    }
    *(float4*)&out[i4] = acc;
}

// ===========================================================================
// qk: qkfull[b, h*768+j] = sum_i qfull[b, h*128+i] * WkT[i][h*768+j]
// RT=64: grid (96, 4), 256 thr, K=128 whole. (R6-proven)
// ===========================================================================
__global__ __launch_bounds__(256, 4) void qk_gemm(const float* __restrict__ qfull,
                                                  const float* __restrict__ WkT,
                                                  float* __restrict__ qkfull)
{
    const int cg = threadIdx.x & 15;
    const int rg = threadIdx.x >> 4;
    const int cb = blockIdx.x, rb = blockIdx.y;
    const int n0 = cb * 64 + cg * 4;
    const int r0 = rb * 64;
    const int aoff = ((cb * 64) / 768) * 128;

    __shared__ float As[64][132];
    for (int e = threadIdx.x * 4; e < 64 * 128; e += 1024) {
        int r = e >> 7, k = e & 127;
        *(float4*)&As[r][k] = *(const float4*)&qfull[(size_t)(r0 + r) * 1024 + aoff + k];
    }
    __syncthreads();

    float4 acc[4];
#pragma unroll
    for (int rr = 0; rr < 4; ++rr) acc[rr] = make_float4(0.f, 0.f, 0.f, 0.f);
    const float* wp = WkT + n0;
#pragma unroll 2
    for (int k = 0; k < 128; k += 4) {
        float4 w0 = *(const float4*)&wp[(size_t)(k + 0) * 6144];
        float4 w1 = *(const float4*)&wp[(size_t)(k + 1) * 6144];
        float4 w2 = *(const float4*)&wp[(size_t)(k + 2) * 6144];
        float4 w3 = *(const float4*)&wp[(size_t)(k + 3) * 6144];
#pragma unroll
        for (int rr = 0; rr < 4; ++rr) {
            float4 a = *(const float4*)&As[rg * 4 + rr][k];
            FMA16(acc[rr], a, w0, w1, w2, w3)
        }
    }
#pragma unroll
    for (int rr = 0; rr < 4; ++rr)
        *(float4*)&qkfull[(size_t)(r0 + rg * 4 + rr) * 6144 + n0] = acc[rr];
}

// ===========================================================================
// attn partial: block = (b, quarter). 4 waves; every 4th unmasked row;
// depth-2 clamped register prefetch (R6-proven). Rotated-head merge
// (R8-proven pattern): 4 rounds, each wave adds 2 distinct heads.
// Writes UNNORMALIZED pctx + psum.
// ===========================================================================
__device__ __forceinline__ float dot12(float4 a0, float4 a1, float4 a2,
                                       float4 x0, float4 x1, float4 x2)
{
    float acc;
    acc = a0.x * x0.x;
    acc = fmaf(a0.y, x0.y, acc);
    acc = fmaf(a0.z, x0.z, acc);
    acc = fmaf(a0.w, x0.w, acc);
    acc = fmaf(a1.x, x1.x, acc);
    acc = fmaf(a1.y, x1.y, acc);
    acc = fmaf(a1.z, x1.z, acc);
    acc = fmaf(a1.w, x1.w, acc);
    acc = fmaf(a2.x, x2.x, acc);
    acc = fmaf(a2.y, x2.y, acc);
    acc = fmaf(a2.z, x2.z, acc);
    acc = fmaf(a2.w, x2.w, acc);
    return acc;
}

__global__ __launch_bounds__(256, 2) void attn_part(const float* __restrict__ text,
                                                    const int* __restrict__ mask,
                                                    const float* __restrict__ qk,
                                                    float* __restrict__ pctx,
                                                    float* __restrict__ psum)
{
    const int bx   = blockIdx.x;          // 1024 = 256 b x 4 quarters
    const int b    = bx >> 2;
    const int qt   = bx & 3;
    const int tid  = threadIdx.x;
    const int wv   = tid >> 6;            // 0..3
    const int lane = tid & 63;

    __shared__ float qk_s[Hh][Dd];        // 24 KB
    __shared__ float ctx_s[Hh][Dd];       // 24 KB
    __shared__ float wsum_s[4][Hh];
    __shared__ int   list_s[128];
    __shared__ int   wcnt_s[2];

    const float* qkp = qk + (size_t)b * (Hh * Dd);
    float* qf = (float*)qk_s;
    float* cf = (float*)ctx_s;
    for (int e = tid * 4; e < Hh * Dd; e += 1024) {
        *(float4*)&qf[e] = *(const float4*)&qkp[e];
        *(float4*)&cf[e] = make_float4(0.f, 0.f, 0.f, 0.f);
    }

    int m = 0, pre = 0, t = 0;
    if (wv < 2) {
        t = qt * 128 + wv * 64 + lane;
        m = mask[(size_t)b * Tt + t];
        unsigned long long bal = __ballot(m != 0);
        pre = __popcll(bal & ((1ull << lane) - 1ull));
        if (lane == 0) wcnt_s[wv] = __popcll(bal);
    }
    __syncthreads();
    if (wv < 2 && m) {
        int base = wv ? wcnt_s[0] : 0;
        list_s[base + pre] = t;
    }
    __syncthreads();
    const int cnt = wcnt_s[0] + wcnt_s[1];

    float s[Hh] = {0.f, 0.f, 0.f, 0.f, 0.f, 0.f, 0.f, 0.f};
    float4 cr[Hh][3];
#pragma unroll
    for (int h = 0; h < Hh; ++h)
#pragma unroll
        for (int c = 0; c < 3; ++c) cr[h][c] = make_float4(0.f, 0.f, 0.f, 0.f);

    const float scale = 0.08838834764831845f;   // 1/sqrt(128)
    const float* tbase = text + (size_t)b * Tt * Dd;

    // depth-2 register prefetch: A = entry e, B = entry e+4, C issued for e+8
    int e = wv;
    float4 xa0, xa1, xa2, xb0, xb1, xb2;
    xa0 = xa1 = xa2 = make_float4(0.f, 0.f, 0.f, 0.f);
    xb0 = xb1 = xb2 = xa0;
    if (e < cnt) {
        const float* tp = tbase + (size_t)list_s[e] * Dd + 4 * lane;
        xa0 = *(const float4*)(tp);
        xa1 = *(const float4*)(tp + 256);
        xa2 = *(const float4*)(tp + 512);
        int e1 = (e + 4 < cnt) ? e + 4 : cnt - 1;
        const float* tq = tbase + (size_t)list_s[e1] * Dd + 4 * lane;
        xb0 = *(const float4*)(tq);
        xb1 = *(const float4*)(tq + 256);
        xb2 = *(const float4*)(tq + 512);
    }
    while (e < cnt) {
        int ei = (e + 8 < cnt) ? e + 8 : cnt - 1;
        const float* tc = tbase + (size_t)list_s[ei] * Dd + 4 * lane;
        float4 xc0 = *(const float4*)(tc);
        float4 xc1 = *(const float4*)(tc + 256);
        float4 xc2 = *(const float4*)(tc + 512);

        float p[Hh];
#pragma unroll
        for (int h = 0; h < Hh; ++h) {
            const float* qh = &qk_s[h][4 * lane];
            float4 a0 = *(const float4*)(qh);
            float4 a1 = *(const float4*)(qh + 256);
            float4 a2 = *(const float4*)(qh + 512);
            p[h] = dot12(a0, a1, a2, xa0, xa1, xa2);
        }
#pragma unroll
        for (int h = 0; h < Hh; ++h) {
            float v = p[h];
            v += __shfl_xor(v, 1);
            v += __shfl_xor(v, 2);
            v += __shfl_xor(v, 4);
            v += __shfl_xor(v, 8);
            v += __shfl_xor(v, 16);
            v += __shfl_xor(v, 32);
            float w = __expf(v * scale);
            s[h] += w;
            cr[h][0].x = fmaf(w, xa0.x, cr[h][0].x);
            cr[h][0].y = fmaf(w, xa0.y, cr[h][0].y);
            cr[h][0].z = fmaf(w, xa0.z, cr[h][0].z);
            cr[h][0].w = fmaf(w, xa0.w, cr[h][0].w);
            cr[h][1].x = fmaf(w, xa1.x, cr[h][1].x);
            cr[h][1].y = fmaf(w, xa1.y, cr[h][1].y);
            cr[h][1].z = fmaf(w, xa1.z, cr[h][1].z);
            cr[h][1].w = fmaf(w, xa1.w, cr[h][1].w);
            cr[h][2].x = fmaf(w, xa2.x, cr[h][2].x);
            cr[h][2].y = fmaf(w, xa2.y, cr[h][2].y);
            cr[h][2].z = fmaf(w, xa2.z, cr[h][2].z);
            cr[h][2].w = fmaf(w, xa2.w, cr[h][2].w);
        }
        xa0 = xb0; xa1 = xb1; xa2 = xb2;
        xb0 = xc0; xb1 = xc1; xb2 = xc2;
        e += 4;
    }

    if (lane == 0) {
#pragma unroll
        for (int h = 0; h < Hh; ++h) wsum_s[wv][h] = s[h];
    }

    // rotated-head merge: round r, wave wv adds heads {(wv+r)&3, 4+((wv+r)&3)}
    for (int rnd = 0; rnd < 4; ++rnd) {
        __syncthreads();
        int hh = (wv + rnd) & 3;
#pragma unroll
        for (int g = 0; g < 2; ++g) {
            int h = hh + g * 4;
            float* cp = &ctx_s[h][4 * lane];
#pragma unroll
            for (int c = 0; c < 3; ++c) {
                float4 cur = *(float4*)(cp + c * 256);
                cur.x += cr[h][c].x;
                cur.y += cr[h][c].y;
                cur.z += cr[h][c].z;
                cur.w += cr[h][c].w;
                *(float4*)(cp + c * 256) = cur;
            }
        }
    }
    __syncthreads();

    if (tid < Hh) {
        float S = wsum_s[0][tid] + wsum_s[1][tid] + wsum_s[2][tid] + wsum_s[3][tid];
        psum[(size_t)bx * Hh + tid] = S;
    }
    float* outp = pctx + (size_t)bx * (Hh * Dd);
    for (int e2 = tid * 4; e2 < Hh * Dd; e2 += 1024)
        *(float4*)&outp[e2] = *(const float4*)&cf[e2];
}

// ===========================================================================
// v: aoslab[ks][b][h*128+i] = sum_{k-slice} ctx[b][h*768+j] * WvT[j][h*128+i]
// ctx = (sum_q pctx[b*4+q]) / (sum_q psum[b*4+q][h]) folded in staging. (R6)
// ===========================================================================
__global__ __launch_bounds__(256, 4) void v_gemm(const float* __restrict__ pctx,
                                                 const float* __restrict__ psum,
                                                 const float* __restrict__ WvT,
                                                 float* __restrict__ aoslab)
{
    const int cg = threadIdx.x & 31;
    const int rg = threadIdx.x >> 5;
    const int h = blockIdx.x, rb = blockIdx.y, ks = blockIdx.z;
    const int n0 = h * 128 + cg * 4;
    const int r0 = rb * 32;
    const int k0 = ks * 128;

    __shared__ float As[32][132];
    __shared__ float sv[32];

    if (threadIdx.x < 32) {
        int row = r0 + threadIdx.x;
        float S = 0.f;
#pragma unroll
        for (int i = 0; i < 4; ++i) S += psum[(size_t)(row * 4 + i) * Hh + h];
        sv[threadIdx.x] = 1.0f / S;
    }
    __syncthreads();
    for (int e = threadIdx.x * 4; e < 32 * 128; e += 1024) {
        int r = e >> 7, k = e & 127;
        size_t col = (size_t)h * 768 + k0 + k;
        float4 acc = make_float4(0.f, 0.f, 0.f, 0.f);
#pragma unroll
        for (int i = 0; i < 4; ++i) {
            float4 v = *(const float4*)&pctx[((size_t)(r0 + r) * 4 + i) * 6144 + col];
            acc.x += v.x; acc.y += v.y; acc.z += v.z; acc.w += v.w;
        }
        float svv = sv[r];
        acc.x *= svv; acc.y *= svv; acc.z *= svv; acc.w *= svv;
        *(float4*)&As[r][k] = acc;
    }
    __syncthreads();

    float4 acc[4];
#pragma unroll
    for (int rr = 0; rr < 4; ++rr) acc[rr] = make_float4(0.f, 0.f, 0.f, 0.f);
    const float* wp = WvT + (size_t)k0 * 1024 + n0;
#pragma unroll 2
    for (int k = 0; k < 128; k += 4) {
        float4 w0 = *(const float4*)&wp[(size_t)(k + 0) * 1024];
        float4 w1 = *(const float4*)&wp[(size_t)(k + 1) * 1024];
        float4 w2 = *(const float4*)&wp[(size_t)(k + 2) * 1024];
        float4 w3 = *(const float4*)&wp[(size_t)(k + 3) * 1024];
#pragma unroll
        for (int rr = 0; rr < 4; ++rr) {
            float4 a = *(const float4*)&As[rg * 4 + rr][k];
            FMA16(acc[rr], a, w0, w1, w2, w3)
        }
    }
    float* cp = aoslab + (size_t)ks * 262144;
#pragma unroll
    for (int rr = 0; rr < 4; ++rr)
        *(float4*)&cp[(size_t)(r0 + rg * 4 + rr) * 1024 + n0] = acc[rr];
}

// ===========================================================================
// redbn: fused h1 slab-fold (+b1) -> h1full AND BN stats -> scale/shift.
// 64 blocks x 256 thr. (R9-proven correct)
// ===========================================================================
__global__ __launch_bounds__(256) void redbn(const float* __restrict__ h1slab,
                                             const float* __restrict__ b1,
                                             const float* __restrict__ gamma,
                                             const float* __restrict__ beta,
                                             float* __restrict__ h1full,
                                             float* __restrict__ scl,
                                             float* __restrict__ shf)
{
    int c8 = threadIdx.x & 7, rg = threadIdx.x >> 3;   // rg 0..31
    int c = blockIdx.x * 8 + c8;
    float bias = b1[c];
    float sum = 0.f, sq = 0.f;
    for (int r = rg; r < Bb; r += 32) {
        float v = bias;
#pragma unroll
        for (int s = 0; s < 8; ++s)
            v += h1slab[(size_t)s * 131072 + (size_t)r * HIDh + c];
        h1full[(size_t)r * HIDh + c] = v;
        sum += v;
        sq = fmaf(v, v, sq);
    }
    __shared__ float ss[32][8], sq_[32][8];
    ss[rg][c8] = sum; sq_[rg][c8] = sq;
    for (int off = 16; off > 0; off >>= 1) {
        __syncthreads();
        if (rg < off) { ss[rg][c8] += ss[rg + off][c8]; sq_[rg][c8] += sq_[rg + off][c8]; }
    }
    __syncthreads();
    if (rg == 0) {
        float mu  = ss[0][c8] * (1.0f / Bb);
        float var = sq_[0][c8] * (1.0f / Bb) - mu * mu;
        float g   = gamma[c] * rsqrtf(var + 1e-5f);
        scl[c] = g;
        shf[c] = fmaf(-mu, g, beta[c]);
    }
}

// ===========================================================================
// Final: out = gelu(scl*h1full + shf) @ W2T + b2. grid (4,16), 256 thr. (R6)
// ===========================================================================
__global__ __launch_bounds__(256, 4) void gelu2(const float* __restrict__ h1full,
                                                const float* __restrict__ scl,
                                                const float* __restrict__ shf,
                                                const float* __restrict__ W2T,
                                                const float* __restrict__ b2,
                                                float* __restrict__ out)
{
    const int cg = threadIdx.x & 15;
    const int rg = threadIdx.x >> 4;
    const int n0 = blockIdx.x * 64 + cg * 4;
    const int r0 = blockIdx.y * 16;

    __shared__ float As[16][132];
    float4 acc = make_float4(0.f, 0.f, 0.f, 0.f);

    for (int k0 = 0; k0 < HIDh; k0 += 128) {
        __syncthreads();
        for (int e = threadIdx.x * 4; e < 2048; e += 1024) {
            int r = e >> 7, k = e & 127;
            float4 v  = *(const float4*)&h1full[(size_t)(r0 + r) * HIDh + k0 + k];
            float4 sc = *(const float4*)&scl[k0 + k];
            float4 sh = *(const float4*)&shf[k0 + k];
            float4 z;
            z.x = fmaf(v.x, sc.x, sh.x);
            z.y = fmaf(v.y, sc.y, sh.y);
            z.z = fmaf(v.z, sc.z, sh.z);
            z.w = fmaf(v.w, sc.w, sh.w);
            z.x = 0.5f * z.x * (1.0f + erff(z.x * 0.70710678118654752f));
            z.y = 0.5f * z.y * (1.0f + erff(z.y * 0.70710678118654752f));
            z.z = 0.5f * z.z * (1.0f + erff(z.z * 0.70710678118654752f));
            z.w = 0.5f * z.w * (1.0f + erff(z.w * 0.70710678118654752f));
            *(float4*)&As[r][k] = z;
        }
        __syncthreads();
        const float* wp = W2T + (size_t)k0 * OUTo + n0;
#pragma unroll 2
        for (int k = 0; k < 128; k += 4) {
            float4 w0 = *(const float4*)&wp[(size_t)(k + 0) * OUTo];
            float4 w1 = *(const float4*)&wp[(size_t)(k + 1) * OUTo];
            float4 w2 = *(const float4*)&wp[(size_t)(k + 2) * OUTo];
            float4 w3 = *(const float4*)&wp[(size_t)(k + 3) * OUTo];
            float4 a = *(const float4*)&As[rg][k];
            FMA16(acc, a, w0, w1, w2, w3)
        }
    }

    float4 bvv = *(const float4*)&b2[n0];
    acc.x += bvv.x; acc.y += bvv.y; acc.z += bvv.z; acc.w += bvv.w;
    *(float4*)&out[(size_t)(r0 + rg) * OUTo + n0] = acc;
}

// ===========================================================================
extern "C" void kernel_launch(void* const* d_in, const int* in_sizes, int n_in,
                              void* d_out, int out_size, void* d_ws, size_t ws_size,
                              hipStream_t stream)
{
    const float* x     = (const float*)d_in[0];
    const float* text  = (const float*)d_in[1];
    const int*   amask = (const int*)d_in[2];
    const float* Wq    = (const float*)d_in[3];
    const float* bq    = (const float*)d_in[4];
    const float* Wk    = (const float*)d_in[5];
    // bk (d_in[6]) cancels in softmax — unused
    const float* Wv    = (const float*)d_in[7];
    const float* bv    = (const float*)d_in[8];
    const float* Wo    = (const float*)d_in[9];
    const float* bo    = (const float*)d_in[10];
    const float* W1    = (const float*)d_in[11];
    const float* b1    = (const float*)d_in[12];
    const float* gamma = (const float*)d_in[13];
    const float* beta  = (const float*)d_in[14];
    const float* W2    = (const float*)d_in[15];
    const float* b2    = (const float*)d_in[16];

    float* ws     = (float*)d_ws;
    float* WqT    = ws;                      // 1048576
    float* WoT    = WqT    + 1048576;        // 1048576
    float* WkT    = WoT    + 1048576;        // 786432  [128][6144]
    float* WvT    = WkT    + 786432;         // 786432  [768][1024]
    float* W1T    = WvT    + 786432;         // 524288  [1024][512]
    float* W2T    = W1T    + 524288;         // 131072  [512][256]
    float* qslab  = W2T    + 131072;         // 8 * 262144
    float* qfull  = qslab  + 2097152;        // 262144
    float* qkfull = qfull  + 262144;         // 1572864
    float* pctx   = qkfull + 1572864;        // 1024 * 6144
    float* psum   = pctx   + 6291456;        // 1024 * 8
    float* aoslab = psum   + 8192;           // 6 * 262144
    float* aofull = aoslab + 1572864;        // 262144
    float* oslab  = aofull + 262144;         // 8 * 262144
    float* ofull  = oslab  + 2097152;        // 262144
    float* h1slab = ofull  + 262144;         // 8 * 131072
    float* h1full = h1slab + 1048576;        // 131072
    float* scl    = h1full + 131072;         // 512
    float* shf    = scl    + 512;            // 512

    // 1. weight transforms
    prep<<<4480, 256, 0, stream>>>(Wq, WqT, Wo, WoT, Wv, WvT, W1, W1T, W2, W2T, Wk, WkT);

    // 2. q slabs = x @ WqT, split-K 8, RT=64, 512 blocks
    gemm_sk<64, 64, 4, 128><<<dim3(16, 4, 8), 256, 0, stream>>>(x, 1024, WqT, 1024, qslab, 256);
    // 3. qfull = fold(qslab) + bq
    reduce_add<8><<<256, 256, 0, stream>>>(qslab, 262144, bq, qfull, 1024, 262144);

    // 4. qk = qfull(per-head) @ WkT, RT=64, 384 blocks
    qk_gemm<<<dim3(96, 4), 256, 0, stream>>>(qfull, WkT, qkfull);

    // 5. masked softmax-context partials over text_feat (quarters, depth-2 PF)
    attn_part<<<1024, 256, 0, stream>>>(text, amask, qkfull, pctx, psum);

    // 6. aoslab = Wv_h · normalize(fold pctx) per head, split-K 6
    v_gemm<<<dim3(8, 8, 6), 256, 0, stream>>>(pctx, psum, WvT, aoslab);
    // 7. aofull = fold(aoslab) + bv
    reduce_add<6><<<256, 256, 0, stream>>>(aoslab, 262144, bv, aofull, 1024, 262144);

    // 8. o slabs = aofull @ WoT, split-K 8, RT=64, 512 blocks
    gemm_sk<64, 64, 4, 128><<<dim3(16, 4, 8), 256, 0, stream>>>(aofull, 1024, WoT, 1024, oslab, 256);
    // 9. ofull = fold(oslab) + bo
    reduce_add<8><<<256, 256, 0, stream>>>(oslab, 262144, bo, ofull, 1024, 262144);

    // 10. h1 slabs = ofull @ W1T, split-K 8, RT=64, 256 blocks
    gemm_sk<64, 64, 4, 128><<<dim3(8, 4, 8), 256, 0, stream>>>(ofull, 1024, W1T, 512, h1slab, 256);

    // 11. fused: h1full = fold(h1slab)+b1, BN stats -> scale/shift
    redbn<<<64, 256, 0, stream>>>(h1slab, b1, gamma, beta, h1full, scl, shf);

    // 12. out = gelu(BN(h1full)) @ W2T + b2
    gelu2<<<dim3(4, 16), 256, 0, stream>>>(h1full, scl, shf, W2T, b2, (float*)d_out);
}

// Round 11
// 202.639 us; speedup vs baseline: 1.3033x; 1.3033x over previous
//
#include <hip/hip_runtime.h>
#include <math.h>

// Sizes (fixed by the problem)
#define Bb   256
#define Tt   512
#define Dd   768
#define Ff   1024
#define Hh   8
#define HIDh 512
#define OUTo 256

// ===========================================================================
// prep: all weight layout transforms in ONE kernel (4480 blocks, float4 I/O).
// ===========================================================================
__device__ __forceinline__ void tr_tile4(const float* __restrict__ in,
                                         float* __restrict__ out,
                                         int R, int C, int cx, int ry,
                                         float (*tile)[33])
{
    int c0 = cx * 32, r0 = ry * 32;
    int r  = threadIdx.x >> 3;          // 0..31
    int c4 = (threadIdx.x & 7) * 4;     // 0,4,...,28
    float4 v = *(const float4*)&in[(size_t)(r0 + r) * C + c0 + c4];
    tile[r][c4 + 0] = v.x;
    tile[r][c4 + 1] = v.y;
    tile[r][c4 + 2] = v.z;
    tile[r][c4 + 3] = v.w;
    __syncthreads();
    float4 o;
    o.x = tile[c4 + 0][r];
    o.y = tile[c4 + 1][r];
    o.z = tile[c4 + 2][r];
    o.w = tile[c4 + 3][r];
    *(float4*)&out[(size_t)(c0 + r) * R + r0 + c4] = o;
}

__global__ __launch_bounds__(256) void prep(const float* __restrict__ Wq, float* __restrict__ WqT,
                                            const float* __restrict__ Wo, float* __restrict__ WoT,
                                            const float* __restrict__ Wv, float* __restrict__ WvT,
                                            const float* __restrict__ W1, float* __restrict__ W1T,
                                            const float* __restrict__ W2, float* __restrict__ W2T,
                                            const float* __restrict__ Wk, float* __restrict__ WkT)
{
    __shared__ float tile[32][33];
    int idx = blockIdx.x;
    if (idx < 1024) {
        tr_tile4(Wq, WqT, 1024, 1024, idx & 31, idx >> 5, tile);
    } else if (idx < 2048) {
        int i2 = idx - 1024;
        tr_tile4(Wo, WoT, 1024, 1024, i2 & 31, i2 >> 5, tile);
    } else if (idx < 2816) {
        int i2 = idx - 2048;                 // Wv: [1024][768]
        tr_tile4(Wv, WvT, 1024, 768, i2 % 24, i2 / 24, tile);
    } else if (idx < 3328) {
        int i2 = idx - 2816;                 // W1: [512][1024]
        tr_tile4(W1, W1T, 512, 1024, i2 & 31, i2 >> 5, tile);
    } else if (idx < 3456) {
        int i2 = idx - 3328;                 // W2: [256][512]
        tr_tile4(W2, W2T, 256, 512, i2 & 15, i2 >> 4, tile);
    } else {
        int i2 = idx - 3456;                 // Wk permute: (h,i,j)->[i][h*768+j]
        int i = i2 >> 3, h = i2 & 7;
        if (threadIdx.x < 192) {
            int j = threadIdx.x * 4;
            *(float4*)&WkT[(size_t)(i * 8 + h) * 768 + j] =
                *(const float4*)&Wk[(size_t)(h * 128 + i) * 768 + j];
        }
    }
}

// 16-FMA micro-tile (4 w-float4 x 1 a-float4)
#define FMA16(acc, a, w0, w1, w2, w3)                         \
    acc.x = fmaf(a.x, w0.x, acc.x); acc.y = fmaf(a.x, w0.y, acc.y); \
    acc.z = fmaf(a.x, w0.z, acc.z); acc.w = fmaf(a.x, w0.w, acc.w); \
    acc.x = fmaf(a.y, w1.x, acc.x); acc.y = fmaf(a.y, w1.y, acc.y); \
    acc.z = fmaf(a.y, w1.z, acc.z); acc.w = fmaf(a.y, w1.w, acc.w); \
    acc.x = fmaf(a.z, w2.x, acc.x); acc.y = fmaf(a.z, w2.y, acc.y); \
    acc.z = fmaf(a.z, w2.z, acc.z); acc.w = fmaf(a.z, w2.w, acc.w); \
    acc.x = fmaf(a.w, w3.x, acc.x); acc.y = fmaf(a.w, w3.y, acc.y); \
    acc.z = fmaf(a.w, w3.z, acc.z); acc.w = fmaf(a.w, w3.w, acc.w);

// ===========================================================================
// Split-K GEMM (plain A): Cslab[ks] = A-slice @ Wt-slice
// RT=64 halves W traffic vs RT=32 (M/RT passes over W).
// ===========================================================================
template<int CT, int RT, int R, int KS>
__global__ __launch_bounds__(256, 4) void gemm_sk(const float* __restrict__ A, int strideA,
                                                  const float* __restrict__ Wt, int N,
                                                  float* __restrict__ Cslab, int M)
{
    constexpr int CG = CT / 4;
    constexpr int RG = RT / R;
    static_assert(CG * RG == 256, "bad tile");
    const int cg = threadIdx.x % CG;
    const int rg = threadIdx.x / CG;
    const int n0 = blockIdx.x * CT + cg * 4;
    const int r0 = blockIdx.y * RT;
    const int k0 = blockIdx.z * KS;

    __shared__ float As[RT][KS + 4];
    for (int e = threadIdx.x * 4; e < RT * KS; e += 1024) {
        int r = e / KS, k = e % KS;
        *(float4*)&As[r][k] = *(const float4*)&A[(size_t)(r0 + r) * strideA + k0 + k];
    }
    __syncthreads();

    float4 acc[R];
#pragma unroll
    for (int rr = 0; rr < R; ++rr) acc[rr] = make_float4(0.f, 0.f, 0.f, 0.f);
    const float* wp = Wt + (size_t)k0 * N + n0;
#pragma unroll 2
    for (int k = 0; k < KS; k += 4) {
        float4 w0 = *(const float4*)&wp[(size_t)(k + 0) * N];
        float4 w1 = *(const float4*)&wp[(size_t)(k + 1) * N];
        float4 w2 = *(const float4*)&wp[(size_t)(k + 2) * N];
        float4 w3 = *(const float4*)&wp[(size_t)(k + 3) * N];
#pragma unroll
        for (int rr = 0; rr < R; ++rr) {
            float4 a = *(const float4*)&As[rg * R + rr][k];
            FMA16(acc[rr], a, w0, w1, w2, w3)
        }
    }
    float* cp = Cslab + (size_t)blockIdx.z * M * N;
#pragma unroll
    for (int rr = 0; rr < R; ++rr)
        *(float4*)&cp[(size_t)(r0 + rg * R + rr) * N + n0] = acc[rr];
}

// ===========================================================================
// reduce_add: out[i] = sum_s slabs[s][i] + bias[i % N]
// ===========================================================================
template<int S>
__global__ __launch_bounds__(256) void reduce_add(const float* __restrict__ slabs,
                                                  size_t slabstride,
                                                  const float* __restrict__ bias,
                                                  float* __restrict__ out, int N, int total)
{
    int i4 = (blockIdx.x * 256 + threadIdx.x) * 4;
    if (i4 >= total) return;
    float4 acc = *(const float4*)&bias[i4 % N];
#pragma unroll
    for (int s = 0; s < S; ++s) {
        float4 v = *(const float4*)(slabs + (size_t)s * slabstride + i4);
        acc.x += v.x; acc.y += v.y; acc.z += v.z; acc.w += v.w;
    }
    *(float4*)&out[i4] = acc;
}

// ===========================================================================
// qk: qkfull[b, h*768+j] = sum_i qfull[b, h*128+i] * WkT[i][h*768+j]
// RT=64: grid (96, 4), 256 thr, CG=16 (64 cols), RG=16 x R=4 rows, K=128 whole.
// ===========================================================================
__global__ __launch_bounds__(256, 4) void qk_gemm(const float* __restrict__ qfull,
                                                  const float* __restrict__ WkT,
                                                  float* __restrict__ qkfull)
{
    const int cg = threadIdx.x & 15;
    const int rg = threadIdx.x >> 4;
    const int cb = blockIdx.x, rb = blockIdx.y;
    const int n0 = cb * 64 + cg * 4;
    const int r0 = rb * 64;
    const int aoff = ((cb * 64) / 768) * 128;   // head * 128 (64 | 768, no straddle)

    __shared__ float As[64][132];
    for (int e = threadIdx.x * 4; e < 64 * 128; e += 1024) {
        int r = e >> 7, k = e & 127;
        *(float4*)&As[r][k] = *(const float4*)&qfull[(size_t)(r0 + r) * 1024 + aoff + k];
    }
    __syncthreads();

    float4 acc[4];
#pragma unroll
    for (int rr = 0; rr < 4; ++rr) acc[rr] = make_float4(0.f, 0.f, 0.f, 0.f);
    const float* wp = WkT + n0;
#pragma unroll 2
    for (int k = 0; k < 128; k += 4) {
        float4 w0 = *(const float4*)&wp[(size_t)(k + 0) * 6144];
        float4 w1 = *(const float4*)&wp[(size_t)(k + 1) * 6144];
        float4 w2 = *(const float4*)&wp[(size_t)(k + 2) * 6144];
        float4 w3 = *(const float4*)&wp[(size_t)(k + 3) * 6144];
#pragma unroll
        for (int rr = 0; rr < 4; ++rr) {
            float4 a = *(const float4*)&As[rg * 4 + rr][k];
            FMA16(acc[rr], a, w0, w1, w2, w3)
        }
    }
#pragma unroll
    for (int rr = 0; rr < 4; ++rr)
        *(float4*)&qkfull[(size_t)(r0 + rg * 4 + rr) * 6144 + n0] = acc[rr];
}

// ===========================================================================
// attn partial (R3-proven structure + depth-2 prefetch): block = (b, quarter).
// 256 thr = 4 waves; wave handles every 4th unmasked row of its quarter with
// clamped-index 2-deep register prefetch. Writes UNNORMALIZED pctx + psum.
// ===========================================================================
__device__ __forceinline__ float dot12(float4 a0, float4 a1, float4 a2,
                                       float4 x0, float4 x1, float4 x2)
{
    float acc;
    acc = a0.x * x0.x;
    acc = fmaf(a0.y, x0.y, acc);
    acc = fmaf(a0.z, x0.z, acc);
    acc = fmaf(a0.w, x0.w, acc);
    acc = fmaf(a1.x, x1.x, acc);
    acc = fmaf(a1.y, x1.y, acc);
    acc = fmaf(a1.z, x1.z, acc);
    acc = fmaf(a1.w, x1.w, acc);
    acc = fmaf(a2.x, x2.x, acc);
    acc = fmaf(a2.y, x2.y, acc);
    acc = fmaf(a2.z, x2.z, acc);
    acc = fmaf(a2.w, x2.w, acc);
    return acc;
}

__global__ __launch_bounds__(256, 2) void attn_part(const float* __restrict__ text,
                                                    const int* __restrict__ mask,
                                                    const float* __restrict__ qk,
                                                    float* __restrict__ pctx,
                                                    float* __restrict__ psum)
{
    const int bx   = blockIdx.x;          // 1024 = 256 b x 4 quarters
    const int b    = bx >> 2;
    const int qt   = bx & 3;
    const int tid  = threadIdx.x;
    const int wv   = tid >> 6;            // 0..3
    const int lane = tid & 63;

    __shared__ float qk_s[Hh][Dd];        // 24 KB
    __shared__ float ctx_s[Hh][Dd];       // 24 KB
    __shared__ float wsum_s[4][Hh];
    __shared__ int   list_s[128];
    __shared__ int   wcnt_s[2];

    const float* qkp = qk + (size_t)b * (Hh * Dd);
    float* qf = (float*)qk_s;
    float* cf = (float*)ctx_s;
    for (int e = tid * 4; e < Hh * Dd; e += 1024) {
        *(float4*)&qf[e] = *(const float4*)&qkp[e];
        *(float4*)&cf[e] = make_float4(0.f, 0.f, 0.f, 0.f);
    }

    int m = 0, pre = 0, t = 0;
    if (wv < 2) {
        t = qt * 128 + wv * 64 + lane;
        m = mask[(size_t)b * Tt + t];
        unsigned long long bal = __ballot(m != 0);
        pre = __popcll(bal & ((1ull << lane) - 1ull));
        if (lane == 0) wcnt_s[wv] = __popcll(bal);
    }
    __syncthreads();
    if (wv < 2 && m) {
        int base = wv ? wcnt_s[0] : 0;
        list_s[base + pre] = t;
    }
    __syncthreads();
    const int cnt = wcnt_s[0] + wcnt_s[1];

    float s[Hh] = {0.f, 0.f, 0.f, 0.f, 0.f, 0.f, 0.f, 0.f};
    float4 cr[Hh][3];
#pragma unroll
    for (int h = 0; h < Hh; ++h)
#pragma unroll
        for (int c = 0; c < 3; ++c) cr[h][c] = make_float4(0.f, 0.f, 0.f, 0.f);

    const float scale = 0.08838834764831845f;   // 1/sqrt(128)
    const float* tbase = text + (size_t)b * Tt * Dd;

    // depth-2 register prefetch: A = entry e, B = entry e+4, C issued for e+8
    int e = wv;
    float4 xa0, xa1, xa2, xb0, xb1, xb2;
    xa0 = xa1 = xa2 = make_float4(0.f, 0.f, 0.f, 0.f);
    xb0 = xb1 = xb2 = xa0;
    if (e < cnt) {
        const float* tp = tbase + (size_t)list_s[e] * Dd + 4 * lane;
        xa0 = *(const float4*)(tp);
        xa1 = *(const float4*)(tp + 256);
        xa2 = *(const float4*)(tp + 512);
        int e1 = (e + 4 < cnt) ? e + 4 : cnt - 1;
        const float* tq = tbase + (size_t)list_s[e1] * Dd + 4 * lane;
        xb0 = *(const float4*)(tq);
        xb1 = *(const float4*)(tq + 256);
        xb2 = *(const float4*)(tq + 512);
    }
    while (e < cnt) {
        int ei = (e + 8 < cnt) ? e + 8 : cnt - 1;
        const float* tc = tbase + (size_t)list_s[ei] * Dd + 4 * lane;
        float4 xc0 = *(const float4*)(tc);
        float4 xc1 = *(const float4*)(tc + 256);
        float4 xc2 = *(const float4*)(tc + 512);

        float p[Hh];
#pragma unroll
        for (int h = 0; h < Hh; ++h) {
            const float* qh = &qk_s[h][4 * lane];
            float4 a0 = *(const float4*)(qh);
            float4 a1 = *(const float4*)(qh + 256);
            float4 a2 = *(const float4*)(qh + 512);
            p[h] = dot12(a0, a1, a2, xa0, xa1, xa2);
        }
#pragma unroll
        for (int h = 0; h < Hh; ++h) {
            float v = p[h];
            v += __shfl_xor(v, 1);
            v += __shfl_xor(v, 2);
            v += __shfl_xor(v, 4);
            v += __shfl_xor(v, 8);
            v += __shfl_xor(v, 16);
            v += __shfl_xor(v, 32);
            float w = __expf(v * scale);
            s[h] += w;
            cr[h][0].x = fmaf(w, xa0.x, cr[h][0].x);
            cr[h][0].y = fmaf(w, xa0.y, cr[h][0].y);
            cr[h][0].z = fmaf(w, xa0.z, cr[h][0].z);
            cr[h][0].w = fmaf(w, xa0.w, cr[h][0].w);
            cr[h][1].x = fmaf(w, xa1.x, cr[h][1].x);
            cr[h][1].y = fmaf(w, xa1.y, cr[h][1].y);
            cr[h][1].z = fmaf(w, xa1.z, cr[h][1].z);
            cr[h][1].w = fmaf(w, xa1.w, cr[h][1].w);
            cr[h][2].x = fmaf(w, xa2.x, cr[h][2].x);
            cr[h][2].y = fmaf(w, xa2.y, cr[h][2].y);
            cr[h][2].z = fmaf(w, xa2.z, cr[h][2].z);
            cr[h][2].w = fmaf(w, xa2.w, cr[h][2].w);
        }
        xa0 = xb0; xa1 = xb1; xa2 = xb2;
        xb0 = xc0; xb1 = xc1; xb2 = xc2;
        e += 4;
    }

    if (lane == 0) {
#pragma unroll
        for (int h = 0; h < Hh; ++h) wsum_s[wv][h] = s[h];
    }

    // deterministic serialized accumulation of per-wave ctx into LDS
    for (int w4 = 0; w4 < 4; ++w4) {
        __syncthreads();
        if (wv == w4) {
#pragma unroll
            for (int h = 0; h < Hh; ++h) {
                float* cp = &ctx_s[h][4 * lane];
#pragma unroll
                for (int c = 0; c < 3; ++c) {
                    float4 cur = *(float4*)(cp + c * 256);
                    cur.x += cr[h][c].x;
                    cur.y += cr[h][c].y;
                    cur.z += cr[h][c].z;
                    cur.w += cr[h][c].w;
                    *(float4*)(cp + c * 256) = cur;
                }
            }
        }
    }
    __syncthreads();

    if (tid < Hh) {
        float S = wsum_s[0][tid] + wsum_s[1][tid] + wsum_s[2][tid] + wsum_s[3][tid];
        psum[(size_t)bx * Hh + tid] = S;
    }
    float* outp = pctx + (size_t)bx * (Hh * Dd);
    for (int e2 = tid * 4; e2 < Hh * Dd; e2 += 1024)
        *(float4*)&outp[e2] = *(const float4*)&cf[e2];
}

// ===========================================================================
// v: aoslab[ks][b][h*128+i] = sum_{k-slice} ctx[b][h*768+j] * WvT[j][h*128+i]
// ctx = (sum_q pctx[b*4+q]) / (sum_q psum[b*4+q][h]) folded in staging.
// grid (8 heads, 8 row-blocks, 6 k-slices), 256 thr.  (R3-proven)
// ===========================================================================
__global__ __launch_bounds__(256, 4) void v_gemm(const float* __restrict__ pctx,
                                                 const float* __restrict__ psum,
                                                 const float* __restrict__ WvT,
                                                 float* __restrict__ aoslab)
{
    const int cg = threadIdx.x & 31;
    const int rg = threadIdx.x >> 5;
    const int h = blockIdx.x, rb = blockIdx.y, ks = blockIdx.z;
    const int n0 = h * 128 + cg * 4;
    const int r0 = rb * 32;
    const int k0 = ks * 128;

    __shared__ float As[32][132];
    __shared__ float sv[32];

    if (threadIdx.x < 32) {
        int row = r0 + threadIdx.x;
        float S = 0.f;
#pragma unroll
        for (int i = 0; i < 4; ++i) S += psum[(size_t)(row * 4 + i) * Hh + h];
        sv[threadIdx.x] = 1.0f / S;
    }
    __syncthreads();
    for (int e = threadIdx.x * 4; e < 32 * 128; e += 1024) {
        int r = e >> 7, k = e & 127;
        size_t col = (size_t)h * 768 + k0 + k;
        float4 acc = make_float4(0.f, 0.f, 0.f, 0.f);
#pragma unroll
        for (int i = 0; i < 4; ++i) {
            float4 v = *(const float4*)&pctx[((size_t)(r0 + r) * 4 + i) * 6144 + col];
            acc.x += v.x; acc.y += v.y; acc.z += v.z; acc.w += v.w;
        }
        float svv = sv[r];
        acc.x *= svv; acc.y *= svv; acc.z *= svv; acc.w *= svv;
        *(float4*)&As[r][k] = acc;
    }
    __syncthreads();

    float4 acc[4];
#pragma unroll
    for (int rr = 0; rr < 4; ++rr) acc[rr] = make_float4(0.f, 0.f, 0.f, 0.f);
    const float* wp = WvT + (size_t)k0 * 1024 + n0;
#pragma unroll 2
    for (int k = 0; k < 128; k += 4) {
        float4 w0 = *(const float4*)&wp[(size_t)(k + 0) * 1024];
        float4 w1 = *(const float4*)&wp[(size_t)(k + 1) * 1024];
        float4 w2 = *(const float4*)&wp[(size_t)(k + 2) * 1024];
        float4 w3 = *(const float4*)&wp[(size_t)(k + 3) * 1024];
#pragma unroll
        for (int rr = 0; rr < 4; ++rr) {
            float4 a = *(const float4*)&As[rg * 4 + rr][k];
            FMA16(acc[rr], a, w0, w1, w2, w3)
        }
    }
    float* cp = aoslab + (size_t)ks * 262144;
#pragma unroll
    for (int rr = 0; rr < 4; ++rr)
        *(float4*)&cp[(size_t)(r0 + rg * 4 + rr) * 1024 + n0] = acc[rr];
}

// ===========================================================================
// BN stats over h1full -> folded scale/shift. 64 blocks x 256 thr.
// ===========================================================================
__global__ __launch_bounds__(256) void bn_stats2(const float* __restrict__ h1full,
                                                 const float* __restrict__ gamma,
                                                 const float* __restrict__ beta,
                                                 float* __restrict__ scl,
                                                 float* __restrict__ shf)
{
    int c8 = threadIdx.x & 7, rg = threadIdx.x >> 3;
    int c = blockIdx.x * 8 + c8;
    float sum = 0.f, sq = 0.f;
    for (int r = rg; r < Bb; r += 32) {
        float v = h1full[(size_t)r * HIDh + c];
        sum += v;
        sq = fmaf(v, v, sq);
    }
    __shared__ float ss[32][8], sq_[32][8];
    ss[rg][c8] = sum; sq_[rg][c8] = sq;
    for (int off = 16; off > 0; off >>= 1) {
        __syncthreads();
        if (rg < off) { ss[rg][c8] += ss[rg + off][c8]; sq_[rg][c8] += sq_[rg + off][c8]; }
    }
    __syncthreads();
    if (rg == 0) {
        float mu  = ss[0][c8] * (1.0f / Bb);
        float var = sq_[0][c8] * (1.0f / Bb) - mu * mu;
        float g   = gamma[c] * rsqrtf(var + 1e-5f);
        scl[c] = g;
        shf[c] = fmaf(-mu, g, beta[c]);
    }
}

// ===========================================================================
// Final: out = gelu(scl*h1full + shf) @ W2T + b2. grid (4,16), 256 thr.
// ===========================================================================
__global__ __launch_bounds__(256, 4) void gelu2(const float* __restrict__ h1full,
                                                const float* __restrict__ scl,
                                                const float* __restrict__ shf,
                                                const float* __restrict__ W2T,
                                                const float* __restrict__ b2,
                                                float* __restrict__ out)
{
    const int cg = threadIdx.x & 15;
    const int rg = threadIdx.x >> 4;
    const int n0 = blockIdx.x * 64 + cg * 4;
    const int r0 = blockIdx.y * 16;

    __shared__ float As[16][132];
    float4 acc = make_float4(0.f, 0.f, 0.f, 0.f);

    for (int k0 = 0; k0 < HIDh; k0 += 128) {
        __syncthreads();
        for (int e = threadIdx.x * 4; e < 2048; e += 1024) {
            int r = e >> 7, k = e & 127;
            float4 v  = *(const float4*)&h1full[(size_t)(r0 + r) * HIDh + k0 + k];
            float4 sc = *(const float4*)&scl[k0 + k];
            float4 sh = *(const float4*)&shf[k0 + k];
            float4 z;
            z.x = fmaf(v.x, sc.x, sh.x);
            z.y = fmaf(v.y, sc.y, sh.y);
            z.z = fmaf(v.z, sc.z, sh.z);
            z.w = fmaf(v.w, sc.w, sh.w);
            z.x = 0.5f * z.x * (1.0f + erff(z.x * 0.70710678118654752f));
            z.y = 0.5f * z.y * (1.0f + erff(z.y * 0.70710678118654752f));
            z.z = 0.5f * z.z * (1.0f + erff(z.z * 0.70710678118654752f));
            z.w = 0.5f * z.w * (1.0f + erff(z.w * 0.70710678118654752f));
            *(float4*)&As[r][k] = z;
        }
        __syncthreads();
        const float* wp = W2T + (size_t)k0 * OUTo + n0;
#pragma unroll 2
        for (int k = 0; k < 128; k += 4) {
            float4 w0 = *(const float4*)&wp[(size_t)(k + 0) * OUTo];
            float4 w1 = *(const float4*)&wp[(size_t)(k + 1) * OUTo];
            float4 w2 = *(const float4*)&wp[(size_t)(k + 2) * OUTo];
            float4 w3 = *(const float4*)&wp[(size_t)(k + 3) * OUTo];
            float4 a = *(const float4*)&As[rg][k];
            FMA16(acc, a, w0, w1, w2, w3)
        }
    }

    float4 bvv = *(const float4*)&b2[n0];
    acc.x += bvv.x; acc.y += bvv.y; acc.z += bvv.z; acc.w += bvv.w;
    *(float4*)&out[(size_t)(r0 + rg) * OUTo + n0] = acc;
}

// ===========================================================================
extern "C" void kernel_launch(void* const* d_in, const int* in_sizes, int n_in,
                              void* d_out, int out_size, void* d_ws, size_t ws_size,
                              hipStream_t stream)
{
    const float* x     = (const float*)d_in[0];
    const float* text  = (const float*)d_in[1];
    const int*   amask = (const int*)d_in[2];
    const float* Wq    = (const float*)d_in[3];
    const float* bq    = (const float*)d_in[4];
    const float* Wk    = (const float*)d_in[5];
    // bk (d_in[6]) cancels in softmax — unused
    const float* Wv    = (const float*)d_in[7];
    const float* bv    = (const float*)d_in[8];
    const float* Wo    = (const float*)d_in[9];
    const float* bo    = (const float*)d_in[10];
    const float* W1    = (const float*)d_in[11];
    const float* b1    = (const float*)d_in[12];
    const float* gamma = (const float*)d_in[13];
    const float* beta  = (const float*)d_in[14];
    const float* W2    = (const float*)d_in[15];
    const float* b2    = (const float*)d_in[16];

    float* ws     = (float*)d_ws;
    float* WqT    = ws;                      // 1048576
    float* WoT    = WqT    + 1048576;        // 1048576
    float* WkT    = WoT    + 1048576;        // 786432  [128][6144]
    float* WvT    = WkT    + 786432;         // 786432  [768][1024]
    float* W1T    = WvT    + 786432;         // 524288  [1024][512]
    float* W2T    = W1T    + 524288;         // 131072  [512][256]
    float* qslab  = W2T    + 131072;         // 8 * 262144
    float* qfull  = qslab  + 2097152;        // 262144
    float* qkfull = qfull  + 262144;         // 1572864
    float* pctx   = qkfull + 1572864;        // 1024 * 6144
    float* psum   = pctx   + 6291456;        // 1024 * 8
    float* aoslab = psum   + 8192;           // 6 * 262144
    float* aofull = aoslab + 1572864;        // 262144
    float* oslab  = aofull + 262144;         // 8 * 262144
    float* ofull  = oslab  + 2097152;        // 262144
    float* h1slab = ofull  + 262144;         // 8 * 131072
    float* h1full = h1slab + 1048576;        // 131072
    float* scl    = h1full + 131072;         // 512
    float* shf    = scl    + 512;            // 512

    // 1. weight transforms
    prep<<<4480, 256, 0, stream>>>(Wq, WqT, Wo, WoT, Wv, WvT, W1, W1T, W2, W2T, Wk, WkT);

    // 2. q slabs = x @ WqT, split-K 8, RT=64, 512 blocks
    gemm_sk<64, 64, 4, 128><<<dim3(16, 4, 8), 256, 0, stream>>>(x, 1024, WqT, 1024, qslab, 256);
    // 3. qfull = fold(qslab) + bq
    reduce_add<8><<<256, 256, 0, stream>>>(qslab, 262144, bq, qfull, 1024, 262144);

    // 4. qk = qfull(per-head) @ WkT, RT=64, 384 blocks
    qk_gemm<<<dim3(96, 4), 256, 0, stream>>>(qfull, WkT, qkfull);

    // 5. masked softmax-context partials over text_feat (quarters, depth-2 PF)
    attn_part<<<1024, 256, 0, stream>>>(text, amask, qkfull, pctx, psum);

    // 6. aoslab = Wv_h · normalize(fold pctx) per head, split-K 6
    v_gemm<<<dim3(8, 8, 6), 256, 0, stream>>>(pctx, psum, WvT, aoslab);
    // 7. aofull = fold(aoslab) + bv
    reduce_add<6><<<256, 256, 0, stream>>>(aoslab, 262144, bv, aofull, 1024, 262144);

    // 8. o slabs = aofull @ WoT, split-K 8, RT=64, 512 blocks
    gemm_sk<64, 64, 4, 128><<<dim3(16, 4, 8), 256, 0, stream>>>(aofull, 1024, WoT, 1024, oslab, 256);
    // 9. ofull = fold(oslab) + bo
    reduce_add<8><<<256, 256, 0, stream>>>(oslab, 262144, bo, ofull, 1024, 262144);

    // 10. h1 slabs = ofull @ W1T, split-K 8, RT=64, 256 blocks
    gemm_sk<64, 64, 4, 128><<<dim3(8, 4, 8), 256, 0, stream>>>(ofull, 1024, W1T, 512, h1slab, 256);
    // 11. h1full = fold(h1slab) + b1
    reduce_add<8><<<128, 256, 0, stream>>>(h1slab, 131072, b1, h1full, 512, 131072);

    // 12. BN stats -> scale/shift
    bn_stats2<<<64, 256, 0, stream>>>(h1full, gamma, beta, scl, shf);

    // 13. out = gelu(BN(h1full)) @ W2T + b2
    gelu2<<<dim3(4, 16), 256, 0, stream>>>(h1full, scl, shf, W2T, b2, (float*)d_out);
}